// Round 5
// baseline (403.618 us; speedup 1.0000x reference)
//
#include <hip/hip_runtime.h>

// Problem constants (from reference)
#define C_FIELDS 12
#define F_FIELDS 4
#define SLOTS    16      // C + F
#define D_DIM    128

using f32x4 = __attribute__((ext_vector_type(4))) float;

// ============================ DIAGNOSTIC ROUND ============================
// Identical to R4 (persistent waves, scalar idx prefetch, plain stores)
// EXCEPT the whole token loop runs TWICE (REPS=2). The second pass rewrites
// identical values (idempotent -> verification-safe). Purpose: push the
// kernel dispatch above the ~173us poison fills so it finally appears in
// the top-5 counter table with FETCH_SIZE / WRITE_SIZE / Occupancy /
// VGPR_Count. Four rounds of structurally different kernels all landed at
// an invariant ~130-145us kernel time (2-3x above my roofline model);
// the model is missing a term and only the kernel's own counters can
// identify it. Revert REPS to 1 next round.
// =========================================================================
#define REPS 2

__global__ __launch_bounds__(256) void emb_fused_kernel(
    const int*   __restrict__ cat,     // [NTOK, 12] int32
    const float* __restrict__ cont,    // [NTOK, 4]
    const float* __restrict__ table,   // [V_TOTAL, 128]
    const float* __restrict__ wc,      // [4, 128]
    const float* __restrict__ bc,      // [4, 128]
    float*       __restrict__ out,     // [NTOK*16, 128]
    int n_tok)
{
    // Exclusive prefix sums of VOCABS {100000,800,200,5000,60,30000,10,8,50,2000,20,16}
    constexpr int OFFS[C_FIELDS] = {
        0, 100000, 100800, 101000, 106000, 106060,
        136060, 136070, 136078, 136128, 138128, 138148
    };

    const int lane = threadIdx.x & 63;
    const int hi   = lane >> 5;                  // row parity within pair
    const int d0   = (lane & 31) << 2;           // fp32 element offset in D

    // wave id is uniform; pin to SGPR so per-token index/cont loads
    // scalarize to s_load.
    const int wave0  = __builtin_amdgcn_readfirstlane(
        (int)((blockIdx.x * blockDim.x + threadIdx.x) >> 6));
    const int nwaves = (int)((gridDim.x * blockDim.x) >> 6);

    // --- loop-invariant cont-field weights: rows 12+2k+hi use field 2k+hi ---
    f32x4 wv[2], bv[2];
#pragma unroll
    for (int k = 0; k < 2; ++k) {
        const int f = 2 * k + hi;
        wv[k] = *reinterpret_cast<const f32x4*>(wc + f * D_DIM + d0);
        bv[k] = *reinterpret_cast<const f32x4*>(bc + f * D_DIM + d0);
    }

    int   sidx[C_FIELDS];
    float sx[F_FIELDS];
    auto load_scalars = [&](int token) {
        const int*   catrow  = cat  + token * C_FIELDS;   // uniform -> s_load
        const float* controw = cont + token * F_FIELDS;
#pragma unroll
        for (int c = 0; c < C_FIELDS; ++c) sidx[c] = catrow[c];
#pragma unroll
        for (int f = 0; f < F_FIELDS; ++f) sx[f] = controw[f];
    };

    for (int rep = 0; rep < REPS; ++rep) {
        int token = wave0;
        if (token >= n_tok) continue;
        load_scalars(token);

        while (true) {
            // per-lane gather offsets (fp32-element units) + padding masks
            uint32_t voff[6];
            float    fmask[6];
#pragma unroll
            for (int k = 0; k < 6; ++k) {
                const uint32_t re = (uint32_t)(OFFS[2*k]   + sidx[2*k])   * (uint32_t)D_DIM;
                const uint32_t ro = (uint32_t)(OFFS[2*k+1] + sidx[2*k+1]) * (uint32_t)D_DIM;
                voff[k] = (hi ? ro : re) + (uint32_t)d0;     // 1 cndmask + 1 add
                const float fe = (sidx[2*k]   != 0) ? 1.f : 0.f;  // scalar
                const float fo = (sidx[2*k+1] != 0) ? 1.f : 0.f;  // scalar
                fmask[k] = hi ? fo : fe;                     // 1 cndmask
            }

            // --- issue all 6 independent table gathers (SGPR base + u32 voffset) ---
            f32x4 v[6];
#pragma unroll
            for (int k = 0; k < 6; ++k)
                v[k] = *reinterpret_cast<const f32x4*>(table + voff[k]);

            // --- cont rows 12..15: x*w + b (pure VALU, overlaps gather latency) ---
            f32x4 rc[2];
#pragma unroll
            for (int k = 0; k < 2; ++k) {
                const float x = hi ? sx[2*k+1] : sx[2*k];
                rc[k].x = fmaf(x, wv[k].x, bv[k].x);
                rc[k].y = fmaf(x, wv[k].y, bv[k].y);
                rc[k].z = fmaf(x, wv[k].z, bv[k].z);
                rc[k].w = fmaf(x, wv[k].w, bv[k].w);
            }

            float* outp = out + (size_t)token * (SLOTS * D_DIM) + hi * D_DIM + d0;

            // --- prefetch NEXT token's scalars while gathers are in flight ---
            const int  next = token + nwaves;
            const bool more = next < n_tok;
            if (more) load_scalars(next);

            // --- padding zeroing + 8 plain stores (wave: 8 KB contiguous) ---
#pragma unroll
            for (int k = 0; k < 6; ++k) {
                f32x4 r = v[k];
                r.x *= fmask[k]; r.y *= fmask[k]; r.z *= fmask[k]; r.w *= fmask[k];
                *reinterpret_cast<f32x4*>(outp + k * (2 * D_DIM)) = r;
            }
#pragma unroll
            for (int k = 0; k < 2; ++k)
                *reinterpret_cast<f32x4*>(outp + (C_FIELDS + 2 * k) * D_DIM) = rc[k];

            if (!more) break;
            token = next;
        }
    }
}

extern "C" void kernel_launch(void* const* d_in, const int* in_sizes, int n_in,
                              void* d_out, int out_size, void* d_ws, size_t ws_size,
                              hipStream_t stream) {
    const int*   cat   = (const int*)d_in[0];
    const float* cont  = (const float*)d_in[1];
    const float* table = (const float*)d_in[2];
    const float* wc    = (const float*)d_in[3];
    const float* bc    = (const float*)d_in[4];
    float*       out   = (float*)d_out;

    const int n_tok = in_sizes[0] / C_FIELDS;    // B*L = 32768

    // Persistent waves: 2048 blocks x 4 waves = 8192 waves = 32 waves/CU on
    // 256 CUs; each wave handles ceil(n_tok/8192) tokens (4 at bench shape).
    const int block = 256;
    int grid = (n_tok + 3) / 4;
    if (grid > 2048) grid = 2048;
    if (grid < 1)    grid = 1;

    emb_fused_kernel<<<grid, block, 0, stream>>>(cat, cont, table, wc, bc, out, n_tok);
}

// Round 6
// 341.809 us; speedup vs baseline: 1.1808x; 1.1808x over previous
//
#include <hip/hip_runtime.h>

// Problem constants (from reference)
#define C_FIELDS 12
#define F_FIELDS 4
#define SLOTS    16      // C + F
#define D_DIM    128
#define V_TOTAL_ROWS 138164   // sum of VOCABS

using f32x4 = __attribute__((ext_vector_type(4))) float;

// R5 findings: warm full pass (gather+store, caches warm) = 56 us marginal;
// kernel(REPS=1) < 120 us => ~60 us is COLD-pass overhead: the harness's
// 1 GiB poison evicts the 70.8 MB table from L2/L3 every iteration, and the
// first-touch gathers are random 512-B reads that can't saturate HBM
// (row-buffer/miss-queue inefficiency), even though unique cold traffic is
// only ~30 MB.
//
// R6 change (single variable): TABLE-WARMING PROLOGUE. The grid streams the
// whole table sequentially (float4, kept alive via empty asm -- no store)
// before the token loop. Sequential streaming refills L3 (256 MB >> 70.8 MB)
// at ~6.3 TB/s (~11 us, spread across 2048 blocks, overlapped with early
// gathers), converting scattered cold HBM misses into L3/L2 hits. The 10
// small fields (4.2 MB total, 10/12 of gather traffic) become L2-resident
// almost immediately.
__global__ __launch_bounds__(256) void emb_fused_kernel(
    const int*   __restrict__ cat,     // [NTOK, 12] int32
    const float* __restrict__ cont,    // [NTOK, 4]
    const float* __restrict__ table,   // [V_TOTAL, 128]
    const float* __restrict__ wc,      // [4, 128]
    const float* __restrict__ bc,      // [4, 128]
    float*       __restrict__ out,     // [NTOK*16, 128]
    int n_tok)
{
    // Exclusive prefix sums of VOCABS {100000,800,200,5000,60,30000,10,8,50,2000,20,16}
    constexpr int OFFS[C_FIELDS] = {
        0, 100000, 100800, 101000, 106000, 106060,
        136060, 136070, 136078, 136128, 138128, 138148
    };

    const int lane = threadIdx.x & 63;
    const int hi   = lane >> 5;                  // row parity within pair
    const int d0   = (lane & 31) << 2;           // fp32 element offset in D

    // ---------------- table-warming prologue ----------------
    // Sequential grid-stride stream of the full table. Values folded into a
    // dummy accumulator kept alive by an empty asm (rule: ablation-via-skip
    // DCE) -- no store, no side effect, just cache allocation.
    {
        const f32x4* tp = reinterpret_cast<const f32x4*>(table);
        const size_t nchunk = (size_t)V_TOTAL_ROWS * (D_DIM / 4);
        const size_t gstride = (size_t)gridDim.x * blockDim.x;
        float acc = 0.f;
        for (size_t i = (size_t)blockIdx.x * blockDim.x + threadIdx.x;
             i < nchunk; i += gstride) {
            const f32x4 t = tp[i];
            acc += t.x + t.y + t.z + t.w;
        }
        asm volatile("" : : "v"(acc));           // keep loads live, no cost
    }
    // --------------------------------------------------------

    // wave id is uniform; pin to SGPR so per-token index/cont loads
    // scalarize to s_load.
    const int wave0  = __builtin_amdgcn_readfirstlane(
        (int)((blockIdx.x * blockDim.x + threadIdx.x) >> 6));
    const int nwaves = (int)((gridDim.x * blockDim.x) >> 6);

    // --- loop-invariant cont-field weights: rows 12+2k+hi use field 2k+hi ---
    f32x4 wv[2], bv[2];
#pragma unroll
    for (int k = 0; k < 2; ++k) {
        const int f = 2 * k + hi;
        wv[k] = *reinterpret_cast<const f32x4*>(wc + f * D_DIM + d0);
        bv[k] = *reinterpret_cast<const f32x4*>(bc + f * D_DIM + d0);
    }

    int   sidx[C_FIELDS];
    float sx[F_FIELDS];
    auto load_scalars = [&](int token) {
        const int*   catrow  = cat  + token * C_FIELDS;   // uniform -> s_load
        const float* controw = cont + token * F_FIELDS;
#pragma unroll
        for (int c = 0; c < C_FIELDS; ++c) sidx[c] = catrow[c];
#pragma unroll
        for (int f = 0; f < F_FIELDS; ++f) sx[f] = controw[f];
    };

    int token = wave0;
    if (token >= n_tok) return;
    load_scalars(token);

    while (true) {
        // per-lane gather offsets (fp32-element units) + padding masks
        uint32_t voff[6];
        float    fmask[6];
#pragma unroll
        for (int k = 0; k < 6; ++k) {
            const uint32_t re = (uint32_t)(OFFS[2*k]   + sidx[2*k])   * (uint32_t)D_DIM;
            const uint32_t ro = (uint32_t)(OFFS[2*k+1] + sidx[2*k+1]) * (uint32_t)D_DIM;
            voff[k] = (hi ? ro : re) + (uint32_t)d0;     // 1 cndmask + 1 add
            const float fe = (sidx[2*k]   != 0) ? 1.f : 0.f;  // scalar
            const float fo = (sidx[2*k+1] != 0) ? 1.f : 0.f;  // scalar
            fmask[k] = hi ? fo : fe;                     // 1 cndmask
        }

        // --- issue all 6 independent table gathers (SGPR base + u32 voffset) ---
        f32x4 v[6];
#pragma unroll
        for (int k = 0; k < 6; ++k)
            v[k] = *reinterpret_cast<const f32x4*>(table + voff[k]);

        // --- cont rows 12..15: x*w + b (pure VALU, overlaps gather latency) ---
        f32x4 rc[2];
#pragma unroll
        for (int k = 0; k < 2; ++k) {
            const float x = hi ? sx[2*k+1] : sx[2*k];
            rc[k].x = fmaf(x, wv[k].x, bv[k].x);
            rc[k].y = fmaf(x, wv[k].y, bv[k].y);
            rc[k].z = fmaf(x, wv[k].z, bv[k].z);
            rc[k].w = fmaf(x, wv[k].w, bv[k].w);
        }

        float* outp = out + (size_t)token * (SLOTS * D_DIM) + hi * D_DIM + d0;

        // --- prefetch NEXT token's scalars while gathers are in flight ---
        const int  next = token + nwaves;
        const bool more = next < n_tok;
        if (more) load_scalars(next);

        // --- padding zeroing + 8 plain stores (wave: 8 KB contiguous) ---
#pragma unroll
        for (int k = 0; k < 6; ++k) {
            f32x4 r = v[k];
            r.x *= fmask[k]; r.y *= fmask[k]; r.z *= fmask[k]; r.w *= fmask[k];
            *reinterpret_cast<f32x4*>(outp + k * (2 * D_DIM)) = r;
        }
#pragma unroll
        for (int k = 0; k < 2; ++k)
            *reinterpret_cast<f32x4*>(outp + (C_FIELDS + 2 * k) * D_DIM) = rc[k];

        if (!more) break;
        token = next;
    }
}

extern "C" void kernel_launch(void* const* d_in, const int* in_sizes, int n_in,
                              void* d_out, int out_size, void* d_ws, size_t ws_size,
                              hipStream_t stream) {
    const int*   cat   = (const int*)d_in[0];
    const float* cont  = (const float*)d_in[1];
    const float* table = (const float*)d_in[2];
    const float* wc    = (const float*)d_in[3];
    const float* bc    = (const float*)d_in[4];
    float*       out   = (float*)d_out;

    const int n_tok = in_sizes[0] / C_FIELDS;    // B*L = 32768

    // Persistent waves: 2048 blocks x 4 waves = 8192 waves = 32 waves/CU on
    // 256 CUs; each wave handles ceil(n_tok/8192) tokens (4 at bench shape).
    const int block = 256;
    int grid = (n_tok + 3) / 4;
    if (grid > 2048) grid = 2048;
    if (grid < 1)    grid = 1;

    emb_fused_kernel<<<grid, block, 0, stream>>>(cat, cont, table, wc, bc, out, n_tok);
}